// Round 1
// baseline (104.328 us; speedup 1.0000x reference)
//
#include <hip/hip_runtime.h>

// Problem constants (from reference): B=64, T=128, D=1024, H=512
#define B_ 64
#define T_ 128
#define D_ 1024
#define H_ 512

// ---------------------------------------------------------------------------
// Kernel A: xs[b,t] = dot(x[b,t,:], w_x) where w_x = fc_w[H:], length D.
// One wave (64 lanes) per (b,t) row; 4 float4 loads per lane = 1024 floats.
// Memory-bound: reads x (33.5 MB) exactly once, coalesced 16B/lane.
// ---------------------------------------------------------------------------
__global__ __launch_bounds__(256) void xs_kernel(const float* __restrict__ x,
                                                 const float* __restrict__ fc_w,
                                                 float* __restrict__ xs) {
    const float* wx = fc_w + H_;
    const int wave = threadIdx.x >> 6;
    const int lane = threadIdx.x & 63;
    const int row  = blockIdx.x * 4 + wave;          // row in [0, B*T)
    const float* base = x + (size_t)row * D_;
    float acc = 0.f;
#pragma unroll
    for (int k = 0; k < 4; ++k) {
        const int idx = k * 256 + lane * 4;          // coalesced 1KB/wave/iter
        float4 v = *(const float4*)(base + idx);
        float4 w = *(const float4*)(wx + idx);
        acc += v.x * w.x + v.y * w.y + v.z * w.z + v.w * w.w;
    }
#pragma unroll
    for (int off = 32; off > 0; off >>= 1)
        acc += __shfl_down(acc, off, 64);
    if (lane == 0) xs[row] = acc;
}

// ---------------------------------------------------------------------------
// Kernel B: per-batch masked suffix logsumexp.
// One block per b; 128 threads. Thread j computes
//   loss(j) = LSE(xs[b, j+2 .. len-1]) - xs[b, j+2]   for j <= len-3,
// all reads from LDS. Then block-reduce loss; cnt_b = len-2.
// ---------------------------------------------------------------------------
__global__ __launch_bounds__(128) void loss_kernel(const int* __restrict__ mask,
                                                   const float* __restrict__ xs,
                                                   float* __restrict__ ploss,
                                                   int* __restrict__ pcnt) {
    __shared__ float sxs[T_];
    __shared__ int   sm[T_];
    __shared__ float sl[T_];
    const int b = blockIdx.x;
    const int t = threadIdx.x;
    sxs[t] = xs[b * T_ + t];
    sm[t]  = mask[b * T_ + t];
    __syncthreads();
    // length = sum(mask row)
    for (int off = 64; off > 0; off >>= 1) {
        if (t < off) sm[t] += sm[t + off];
        __syncthreads();
    }
    const int len = sm[0];                            // guaranteed >= 3

    float loss = 0.f;
    if (t <= len - 3) {
        const int p0 = t + 2;
        float m = sxs[p0];
        for (int p = p0 + 1; p < len; ++p) m = fmaxf(m, sxs[p]);
        float s = 0.f;
        for (int p = p0; p < len; ++p) s += __expf(sxs[p] - m);
        loss = m + __logf(s) - sxs[p0];
    }
    sl[t] = loss;
    __syncthreads();
    for (int off = 64; off > 0; off >>= 1) {
        if (t < off) sl[t] += sl[t + off];
        __syncthreads();
    }
    if (t == 0) { ploss[b] = sl[0]; pcnt[b] = len - 2; }
}

// ---------------------------------------------------------------------------
// Kernel C: final reduce over B=64 partials (exactly one wave) + divide.
// ---------------------------------------------------------------------------
__global__ __launch_bounds__(64) void final_kernel(const float* __restrict__ ploss,
                                                   const int* __restrict__ pcnt,
                                                   float* __restrict__ out) {
    const int lane = threadIdx.x;
    float l = ploss[lane];
    float c = (float)pcnt[lane];
#pragma unroll
    for (int off = 32; off > 0; off >>= 1) {
        l += __shfl_down(l, off, 64);
        c += __shfl_down(c, off, 64);
    }
    if (lane == 0) out[0] = l / c;                    // cnt >= 64 always (>0)
}

extern "C" void kernel_launch(void* const* d_in, const int* in_sizes, int n_in,
                              void* d_out, int out_size, void* d_ws, size_t ws_size,
                              hipStream_t stream) {
    // setup_inputs order: encoder_output, mask, W_ih, W_hh, b_ih, b_hh, fc_w, fc_b
    const float* x    = (const float*)d_in[0];
    const int*   mask = (const int*)d_in[1];
    const float* fc_w = (const float*)d_in[6];
    // W_ih/W_hh/b_ih/b_hh/fc_b/w_h cancel analytically in lse - logits[...,0].
    float* out = (float*)d_out;

    // workspace layout
    float* xs    = (float*)d_ws;            // B*T floats
    float* ploss = xs + B_ * T_;            // B floats
    int*   pcnt  = (int*)(ploss + B_);      // B ints

    xs_kernel<<<(B_ * T_) / 4, 256, 0, stream>>>(x, fc_w, xs);
    loss_kernel<<<B_, 128, 0, stream>>>(mask, xs, ploss, pcnt);
    final_kernel<<<1, 64, 0, stream>>>(ploss, pcnt, out);
}